// Round 1
// 234.262 us; speedup vs baseline: 1.1372x; 1.1372x over previous
//
#include <hip/hip_runtime.h>
#include <hip/hip_fp16.h>

// Fused MSE + SSIM loss, 32x3x512x512 fp32, MI355X — R5.
// Counters (R4): VALUBusy ~105%, MfmaUtil 0, HBM 19% -> pure VALU-issue bound.
// Changes vs R4:
//  (1) S/D algebra: conv fields 5 -> 4 (S=P+T, D=P-T, S^2, D^2).
//      mu1^2+mu2^2=(A^2+B^2)/2, 2mu1mu2=(A^2-B^2)/2, conv(P^2)+conv(T^2)=(X+Y)/2,
//      conv(PT)=(X-Y)/4 with A=conv(S),B=conv(D),X=conv(S^2),Y=conv(D^2).
//      MSE = sum(D^2) comes free from the d values.
//  (2) Horizontal conv in packed fp16 (v_pk_fma_f16) using staggered pairs
//      (odd-offset half2 built with one v_alignbit_b32). 8 outputs/item.
//  (3) TH 16->32: row-halo factor 1.625 -> 1.3125. LDS 21.5 KB.
//  (4) Slot-spread LDS layout col=8*m+q keeps 128B-strided b128 writes
//      conflict-free; stage B un-permutes with one index swizzle.
//  (5) Interior blocks (65.6%) skip all load guards via a uniform branch.

#define WSZ   512
#define TW    64
#define TH    32
#define HALO  5
#define IN_H  (TH + 2*HALO)    // 42 rows of horizontal-pass output
#define NPOS  32               // float4 (4-field half2 quad) slots per row
#define GX    (WSZ / TW)       // 8
#define GY    (WSZ / TH)       // 16
#define NSLOT 64
#define SSIM_C1 0.0001f
#define SSIM_C2 0.0009f

// 11-tap gaussian, sigma=1.5, normalized
#define W0 0.00102838f
#define W1 0.00759876f
#define W2 0.03600080f
#define W3 0.10936080f
#define W4 0.21300560f
#define W5 0.26601170f

static __device__ __forceinline__ __half2 pk(float a, float b) {
    return __builtin_bit_cast(__half2, __builtin_amdgcn_cvt_pkrtz(a, b));
}
// staggered pair: (lo.hi, hi.lo)  == (x[2u+1], x[2u+2])
static __device__ __forceinline__ __half2 stagger(__half2 hi, __half2 lo) {
    return __builtin_bit_cast(__half2,
        __builtin_amdgcn_alignbit(__builtin_bit_cast(unsigned, hi),
                                  __builtin_bit_cast(unsigned, lo), 16));
}

__launch_bounds__(256, 6)
__global__ void fused_mse_ssim(const float* __restrict__ P,
                               const float* __restrict__ T,
                               float* __restrict__ ws) {
    __shared__ float4 sAB[IN_H][NPOS];   // fields per slot: S, D, SS, DD (half2)
    __shared__ float  red[2][4];

    const int tid = threadIdx.x;
    const int gx0 = blockIdx.x * TW;
    const int gy0 = blockIdx.y * TH;
    const size_t plane = (size_t)blockIdx.z * (WSZ * (size_t)WSZ);
    const float* Pp = P + plane;
    const float* Tp = T + plane;

    const float gwf[11] = {W0,W1,W2,W3,W4,W5,W4,W3,W2,W1,W0};
    unsigned gwh[11];   // half2(w,w) bit patterns, forced wave-uniform -> SGPR
    #pragma unroll
    for (int k = 0; k < 11; ++k)
        gwh[k] = __builtin_amdgcn_readfirstlane(
                     __builtin_bit_cast(unsigned, __float2half2_rn(gwf[k])));

    float mse = 0.f;

    const bool interior = (blockIdx.x != 0) && (blockIdx.x != GX - 1) &&
                          (blockIdx.y != 0) && (blockIdx.y != GY - 1);

    // ---- stage A: packed-fp16 horizontal 11-tap on S,D,S^2,D^2; MSE folded in.
    // item = one row r (of 42) x 8 output px. 336 items.
    for (int it = tid; it < IN_H * 8; it += 256) {
        const int r  = it >> 3;
        const int q  = it & 7;
        const int gy = gy0 - HALO + r;
        const int cb = gx0 + q * 8 - 8;            // leftmost loaded px (16B aligned)
        const float* prow = Pp + ((long)gy * WSZ + cb);
        const float* trow = Tp + ((long)gy * WSZ + cb);
        const bool mrow = ((unsigned)(r - HALO) < (unsigned)TH);

        // aligned half2 pairs of s=p+t and d=p-t over px 0..23
        __half2 As[12], Ad[12];

        if (interior) {
            #pragma unroll
            for (int b = 0; b < 6; ++b) {
                const float4 pv = *(const float4*)(prow + 4 * b);
                const float4 tv = *(const float4*)(trow + 4 * b);
                const float s0 = pv.x + tv.x, s1 = pv.y + tv.y;
                const float s2 = pv.z + tv.z, s3 = pv.w + tv.w;
                const float d0 = pv.x - tv.x, d1 = pv.y - tv.y;
                const float d2 = pv.z - tv.z, d3 = pv.w - tv.w;
                As[2*b]   = pk(s0, s1); As[2*b+1] = pk(s2, s3);
                Ad[2*b]   = pk(d0, d1); Ad[2*b+1] = pk(d2, d3);
                if ((b == 2 || b == 3) && mrow) {   // px 8..15 = the tile px
                    mse = fmaf(d0, d0, mse); mse = fmaf(d1, d1, mse);
                    mse = fmaf(d2, d2, mse); mse = fmaf(d3, d3, mse);
                }
            }
        } else {
            const bool rv = ((unsigned)gy < (unsigned)WSZ);
            #pragma unroll
            for (int b = 0; b < 6; ++b) {
                const unsigned c = (unsigned)(cb + 4 * b);
                float4 pv = make_float4(0.f, 0.f, 0.f, 0.f);
                float4 tv = make_float4(0.f, 0.f, 0.f, 0.f);
                if (rv && c < (unsigned)WSZ) {
                    pv = *(const float4*)(prow + 4 * b);
                    tv = *(const float4*)(trow + 4 * b);
                }
                const float s0 = pv.x + tv.x, s1 = pv.y + tv.y;
                const float s2 = pv.z + tv.z, s3 = pv.w + tv.w;
                const float d0 = pv.x - tv.x, d1 = pv.y - tv.y;
                const float d2 = pv.z - tv.z, d3 = pv.w - tv.w;
                As[2*b]   = pk(s0, s1); As[2*b+1] = pk(s2, s3);
                Ad[2*b]   = pk(d0, d1); Ad[2*b+1] = pk(d2, d3);
                if ((b == 2 || b == 3) && mrow) {
                    mse = fmaf(d0, d0, mse); mse = fmaf(d1, d1, mse);
                    mse = fmaf(d2, d2, mse); mse = fmaf(d3, d3, mse);
                }
            }
        }

        // packed conv: output pair m (=out px 2m,2m+1) needs v[3+2m+k], k=0..10
        const __half2 z = __float2half2_rn(0.f);
        __half2 aS[4]  = {z, z, z, z};
        __half2 aD[4]  = {z, z, z, z};
        __half2 aSS[4] = {z, z, z, z};
        __half2 aDD[4] = {z, z, z, z};

        #pragma unroll
        for (int jj = 0; jj <= 16; ++jj) {
            const int j = jj + 3;                  // pair start px
            __half2 vs, vd;
            if (j & 1) {
                vs = stagger(As[(j >> 1) + 1], As[j >> 1]);
                vd = stagger(Ad[(j >> 1) + 1], Ad[j >> 1]);
            } else {
                vs = As[j >> 1];
                vd = Ad[j >> 1];
            }
            const __half2 vss = __hmul2(vs, vs);
            const __half2 vdd = __hmul2(vd, vd);
            #pragma unroll
            for (int m = 0; m < 4; ++m) {
                const int k = jj - 2 * m;
                if (k >= 0 && k < 11) {
                    const __half2 w = __builtin_bit_cast(__half2, gwh[k]);
                    aS[m]  = __hfma2(w, vs,  aS[m]);
                    aD[m]  = __hfma2(w, vd,  aD[m]);
                    aSS[m] = __hfma2(w, vss, aSS[m]);
                    aDD[m] = __hfma2(w, vdd, aDD[m]);
                }
            }
        }

        // slot-spread store: position pos=4q+m lives at col 8m+q
        #pragma unroll
        for (int m = 0; m < 4; ++m)
            sAB[r][8 * m + q] = make_float4(
                __builtin_bit_cast(float, aS[m]),  __builtin_bit_cast(float, aD[m]),
                __builtin_bit_cast(float, aSS[m]), __builtin_bit_cast(float, aDD[m]));
    }
    __syncthreads();

    // ---- stage B: vertical 11-tap (packed fp16), 4 output rows per thread ----
    const int q2  = tid & 31;                          // half2 position in row
    const int col = ((q2 & 3) << 3) | (q2 >> 2);       // un-permute storage col
    const int y0  = (tid >> 5) << 2;                   // 0,4,...,28

    const __half2 z2 = __float2half2_rn(0.f);
    __half2 acc[4][4];
    #pragma unroll
    for (int a = 0; a < 4; ++a) {
        acc[a][0] = z2; acc[a][1] = z2; acc[a][2] = z2; acc[a][3] = z2;
    }

    #pragma unroll
    for (int j = 0; j < 14; ++j) {                     // rows y0 .. y0+13
        const float4 ab = sAB[y0 + j][col];
        const __half2 hS  = __builtin_bit_cast(__half2, ab.x);
        const __half2 hD  = __builtin_bit_cast(__half2, ab.y);
        const __half2 hSS = __builtin_bit_cast(__half2, ab.z);
        const __half2 hDD = __builtin_bit_cast(__half2, ab.w);
        #pragma unroll
        for (int a = 0; a < 4; ++a) {
            const int k = j - a;
            if (k >= 0 && k < 11) {
                const __half2 w = __builtin_bit_cast(__half2, gwh[k]);
                acc[a][0] = __hfma2(w, hS,  acc[a][0]);
                acc[a][1] = __hfma2(w, hD,  acc[a][1]);
                acc[a][2] = __hfma2(w, hSS, acc[a][2]);
                acc[a][3] = __hfma2(w, hDD, acc[a][3]);
            }
        }
    }

    // ---- SSIM epilogue (fp32) ----
    // A=conv(S), B=conv(D), X=conv(S^2), Y=conv(D^2):
    //   2*mu12+C1      = 0.5*(A^2-B^2) + C1
    //   mu1^2+mu2^2+C1 = 0.5*(A^2+B^2) + C1
    //   2*s12+C2       = 0.5*((X-Y) - (A^2-B^2)) + C2
    //   s1+s2+C2       = 0.5*((X+Y) - (A^2+B^2)) + C2
    float ssim = 0.f;
    #pragma unroll
    for (int a = 0; a < 4; ++a) {
        const float2 Av = __half22float2(acc[a][0]);
        const float2 Bv = __half22float2(acc[a][1]);
        const float2 Xv = __half22float2(acc[a][2]);
        const float2 Yv = __half22float2(acc[a][3]);
        #pragma unroll
        for (int e = 0; e < 2; ++e) {
            const float A = e ? Av.y : Av.x;
            const float B = e ? Bv.y : Bv.x;
            const float X = e ? Xv.y : Xv.x;
            const float Y = e ? Yv.y : Yv.x;
            const float a2 = A * A;
            const float b2 = B * B;
            const float P1 = a2 + b2;
            const float M1 = a2 - b2;
            const float num1 = fmaf(0.5f, M1, SSIM_C1);
            const float den1 = fmaf(0.5f, P1, SSIM_C1);
            const float num2 = fmaf(0.5f, (X - Y) - M1, SSIM_C2);
            const float den2 = fmaf(0.5f, (X + Y) - P1, SSIM_C2);
            ssim = fmaf(num1 * num2, __builtin_amdgcn_rcpf(den1 * den2), ssim);
        }
    }

    // ---- reduction: wave shuffle -> LDS -> 2 atomics into a spread slot ----
    #pragma unroll
    for (int off = 32; off > 0; off >>= 1) {
        mse  += __shfl_down(mse, off);
        ssim += __shfl_down(ssim, off);
    }
    const int wid = tid >> 6;
    if ((tid & 63) == 0) { red[0][wid] = mse; red[1][wid] = ssim; }
    __syncthreads();
    if (tid == 0) {
        const float m = red[0][0] + red[0][1] + red[0][2] + red[0][3];
        const float s = red[1][0] + red[1][1] + red[1][2] + red[1][3];
        const int bid  = (blockIdx.z * gridDim.y + blockIdx.y) * gridDim.x + blockIdx.x;
        const int slot = (bid & (NSLOT - 1)) * 16;     // 64B apart
        atomicAdd(&ws[slot + 0], m);
        atomicAdd(&ws[slot + 1], s);
    }
}

__global__ void finalize_loss(const float* __restrict__ ws,
                              float* __restrict__ out, float invN) {
    const int t = threadIdx.x;           // 64 threads
    float m = ws[t * 16 + 0];
    float s = ws[t * 16 + 1];
    #pragma unroll
    for (int off = 32; off > 0; off >>= 1) {
        m += __shfl_down(m, off);
        s += __shfl_down(s, off);
    }
    if (t == 0) out[0] = m * invN + 0.01f * (1.f - s * invN);
}

extern "C" void kernel_launch(void* const* d_in, const int* in_sizes, int n_in,
                              void* d_out, int out_size, void* d_ws, size_t ws_size,
                              hipStream_t stream) {
    const float* P = (const float*)d_in[0];
    const float* T = (const float*)d_in[1];
    float* out = (float*)d_out;
    float* ws  = (float*)d_ws;

    const int planes = in_sizes[0] / (WSZ * WSZ);     // 96
    const float invN = 1.f / (float)in_sizes[0];

    (void)hipMemsetAsync(ws, 0, NSLOT * 16 * sizeof(float), stream);
    dim3 grid(GX, GY, planes);
    fused_mse_ssim<<<grid, 256, 0, stream>>>(P, T, ws);
    finalize_loss<<<1, 64, 0, stream>>>(ws, out, invN);
}